// Round 3
// baseline (332.376 us; speedup 1.0000x reference)
//
#include <hip/hip_runtime.h>

// CandidateScorer on MI355X (gfx950).
//
// Restructured math (exact rewrite of the reference):
//   gp-part of combined is candidate-independent      -> folded into bias b1'
//   go/to gathers take only 361 distinct values each  -> precomputed tables
//   h1[n,j] = relu(T_go[go[n],j] + T_to[to[n],j] + (cand @ W1c)[n,j] + b1'[j])
//   scores  = relu(h1 @ W2 + b2) @ W3 + b3   (GEMM3 fused into GEMM2 epilogue)
//
// R1: XCD-aware swizzle (GEMM2 FETCH 529->93 MB), LDS-staged h1 stores.
// R2: tail attack — GEMM1 epilogue via LDS tsum (coalesced T-gathers),
//     parallel b1p, ttab 8-pos reuse, tiled w2 transpose, fused misc kernel.

using bf16x8 = __attribute__((ext_vector_type(8))) __bf16;
using f32x4  = __attribute__((ext_vector_type(4))) float;
using i32x4  = __attribute__((ext_vector_type(4))) int;

__device__ __forceinline__ unsigned short f2bf(float f) {
  unsigned int u = __float_as_uint(f);
  u += 0x7fffu + ((u >> 16) & 1u);          // round-to-nearest-even
  return (unsigned short)(u >> 16);
}

// Async global->LDS, 16B per lane. LDS dest is wave-uniform base + lane*16.
__device__ __forceinline__ void async_copy16(const void* g, void* l) {
  __builtin_amdgcn_global_load_lds(
      (__attribute__((address_space(1))) void*)(unsigned long long)g,
      (__attribute__((address_space(3))) void*)(unsigned int)(unsigned long long)l,
      16, 0, 0);
}

// ---------------------------------------------------------------- prep kernels

// gp[c] = mean over 19x19 of pfm[c]. one wave per channel.
__global__ void pool_kernel(const float* __restrict__ pfm, float* __restrict__ gp) {
  int c = blockIdx.x;
  int lane = threadIdx.x;
  float s = 0.f;
  for (int i = lane; i < 361; i += 64) s += pfm[c * 361 + i];
#pragma unroll
  for (int off = 32; off > 0; off >>= 1) s += __shfl_down(s, off, 64);
  if (lane == 0) gp[c] = s * (1.0f / 361.0f);
}

// b1p[j] += sum over 8 channels of gp[c] * W1[512+c][j]  (b1p pre-init to b1)
// 128 blocks: (jc 0..3) x (cchunk 0..31) — full-GPU parallelism vs R2's 4 blocks.
__global__ void b1p_kernel(const float* __restrict__ W1, const float* __restrict__ gp,
                           float* __restrict__ b1p) {
  int bx = blockIdx.x;
  int j = (bx & 3) * 256 + threadIdx.x;
  int c0 = (bx >> 2) * 8;
  float acc = 0.f;
#pragma unroll
  for (int i = 0; i < 8; i++)
    acc += gp[c0 + i] * W1[(size_t)(512 + c0 + i) * 1024 + j];
  atomicAdd(&b1p[j], acc);
}

// T[s][pos][j] = sum_c pfm[c][pos] * W1[s*256+c][j]; 8 positions per block
// so the coalesced W1 read is reused 8x (halves L2 traffic vs 4).
__global__ void ttab_kernel(const float* __restrict__ pfm, const float* __restrict__ W1,
                            float* __restrict__ T) {
  int bx = blockIdx.x;              // 2 * 46 * 4 = 368 blocks
  int s = bx / 184;
  int rem = bx % 184;
  int p8 = rem >> 2;
  int jc = rem & 3;
  int t = threadIdx.x;
  int j = jc * 256 + t;
  __shared__ float pf[8][256];
#pragma unroll
  for (int i = 0; i < 8; i++) {
    int p = p8 * 8 + i;
    pf[i][t] = (p < 361) ? pfm[t * 361 + p] : 0.f;   // t = channel
  }
  __syncthreads();
  float acc[8] = {0.f, 0.f, 0.f, 0.f, 0.f, 0.f, 0.f, 0.f};
  for (int c = 0; c < 256; c++) {
    float w = W1[(size_t)(s * 256 + c) * 1024 + j];
#pragma unroll
    for (int i = 0; i < 8; i++) acc[i] += pf[i][c] * w;
  }
#pragma unroll
  for (int i = 0; i < 8; i++) {
    int p = p8 * 8 + i;
    if (p < 361) T[((size_t)s * 361 + p) * 1024 + j] = acc[i];
  }
}

// Fused small jobs, partitioned by block range:
//   [0,16384)      cand f32->bf16
//   [16384,16640)  go/to decode
//   [16640,16896)  scores = b3
//   [16896,16900)  b1p = b1            (atomic target init; runs before b1p_kernel)
//   [16900,17156)  w1cT[n][k] = bf16(W1[768+k][n])
__global__ void misc_kernel(const float* __restrict__ cand, unsigned short* __restrict__ cand_bf,
                            int* __restrict__ go_off, int* __restrict__ to_off,
                            float* __restrict__ scores, const float* __restrict__ b3,
                            const float* __restrict__ b1, float* __restrict__ b1p,
                            const float* __restrict__ W1, unsigned short* __restrict__ w1cT) {
  int bx = blockIdx.x, t = threadIdx.x;
  if (bx < 16384) {
    int i = bx * 256 + t;
    cand_bf[i] = f2bf(cand[i]);
  } else if (bx < 16640) {
    int n = (bx - 16384) * 256 + t;
    const float* cf = cand + (size_t)n * 64;
    int gr = min(max((int)(cf[5] * 18.0f), 0), 18);
    int gc = min(max((int)(cf[6] * 18.0f), 0), 18);
    int tr = min(max((int)(cf[7] * 18.0f), 0), 18);
    int tc = min(max((int)(cf[8] * 18.0f), 0), 18);
    go_off[n] = gr * 19 + gc;
    to_off[n] = tr * 19 + tc;
  } else if (bx < 16896) {
    scores[(bx - 16640) * 256 + t] = b3[0];
  } else if (bx < 16900) {
    int j = (bx - 16896) * 256 + t;
    b1p[j] = b1[j];
  } else {
    int o = (bx - 16900) * 256 + t;  // < 65536
    int n = o >> 6, k = o & 63;
    w1cT[o] = f2bf(W1[(size_t)(768 + k) * 1024 + n]);
  }
}

// w2T[n][k] = bf16(W2[k][n]) via 64x64 LDS tiles — coalesced on both sides.
__global__ void w2t_kernel(const float* __restrict__ W2, unsigned short* __restrict__ w2T) {
  __shared__ float Ts[64][65];
  int bx = blockIdx.x;              // 256 tiles (16 x 16)
  int kt = bx >> 4, nt = bx & 15;
  int tid = threadIdx.x;
#pragma unroll
  for (int i = 0; i < 4; i++) {
    int c = i * 256 + tid;          // 1024 f32x4 chunks
    int r = c >> 4, ch = c & 15;
    f32x4 v = *(const f32x4*)&W2[(size_t)(kt * 64 + r) * 1024 + nt * 64 + ch * 4];
    Ts[r][ch * 4 + 0] = v[0]; Ts[r][ch * 4 + 1] = v[1];
    Ts[r][ch * 4 + 2] = v[2]; Ts[r][ch * 4 + 3] = v[3];
  }
  __syncthreads();
#pragma unroll
  for (int i = 0; i < 2; i++) {
    int c = i * 256 + tid;          // 512 out-chunks of 8 bf16
    int n = c >> 3, ch = c & 7;
    unsigned short pack[8];
#pragma unroll
    for (int j = 0; j < 8; j++) pack[j] = f2bf(Ts[ch * 8 + j][n]);
    *(i32x4*)&w2T[(size_t)(nt * 64 + n) * 1024 + kt * 64 + ch * 8] = *(i32x4*)pack;
  }
}

// ---------------------------------------------------------------- GEMM (BT)

// C(M x 1024) = A(M x K, bf16, row-major) * BT(1024 x K, bf16, row-major)^T
// 128x128 tile, BK=32, 4 waves, 4x4 mfma_f32_16x16x32_bf16 per wave.
// XCD-aware block->tile mapping: 8 consecutive blocks on one XCD share mtile.
// EPI==0: h1 epilogue. T_go+T_to+bias restaged into LDS tsum[128][132] with
//         coalesced f32x4 loads (R2 did 192 divergent scalar gathers/thread),
//         then bf16 tile re-staged through the SAME LDS for coalesced stores.
// EPI==1: score epilogue (relu(x+b2) dot w3, shfl-reduce over 16 cols, atomicAdd)
template <int EPI>
__launch_bounds__(256, 2)
__global__ void gemm_bt(const unsigned short* __restrict__ A,
                        const unsigned short* __restrict__ BT,
                        int K,
                        unsigned short* __restrict__ h1out,
                        const float* __restrict__ Ttab,
                        const int* __restrict__ go_off,
                        const int* __restrict__ to_off,
                        const float* __restrict__ bias,
                        const float* __restrict__ w3,
                        float* __restrict__ scores) {
  // EPI==0 unions: {As 8K | Bs 8K} during K-loop, tsum 128*132*4=67584 in
  // epilogue phase 1, Cs 128*136*2=34816 in phase 2.
  __shared__ __align__(16) char smem[EPI == 0 ? 67584 : 16384];
  unsigned short* As = (unsigned short*)smem;          // [row][k] 8KB
  unsigned short* Bs = (unsigned short*)(smem + 8192); // [n][k]   8KB

  const int tid  = threadIdx.x;
  const int lane = tid & 63;
  const int wave = tid >> 6;
  const int wm   = wave & 1;
  const int wn   = wave >> 1;
  const int quad = lane >> 4;
  const int r16  = lane & 15;

  const int bx    = blockIdx.x;
  const int xcd   = bx & 7;
  const int seq   = bx >> 3;
  const int ntile = seq & 7;
  const int mtile = ((seq >> 3) << 3) | xcd;
  const long rowbase = (long)mtile * 128;
  const int  colbase = ntile * 128;

  const f32x4 zero4 = {0.f, 0.f, 0.f, 0.f};
  f32x4 acc[4][4];
#pragma unroll
  for (int i = 0; i < 4; i++)
#pragma unroll
    for (int j = 0; j < 4; j++) acc[i][j] = zero4;

  const int row0 = tid >> 2, cc0 = tid & 3;
  const int row1 = (tid + 256) >> 2, cc1 = (tid + 256) & 3;
  unsigned short* lA0 = &As[(wave * 64) * 8];          // wave-uniform bases
  unsigned short* lA1 = &As[(256 + wave * 64) * 8];
  unsigned short* lB0 = &Bs[(wave * 64) * 8];
  unsigned short* lB1 = &Bs[(256 + wave * 64) * 8];
  const unsigned short* gA0 = A + (rowbase + row0) * K + cc0 * 8;
  const unsigned short* gA1 = A + (rowbase + row1) * K + cc1 * 8;
  const unsigned short* gB0 = BT + (long)(colbase + row0) * K + cc0 * 8;
  const unsigned short* gB1 = BT + (long)(colbase + row1) * K + cc1 * 8;

  for (int k0 = 0; k0 < K; k0 += 32) {
    async_copy16(gA0 + k0, lA0);
    async_copy16(gA1 + k0, lA1);
    async_copy16(gB0 + k0, lB0);
    async_copy16(gB1 + k0, lB1);
    __syncthreads();

    bf16x8 af[4], bfv[4];
#pragma unroll
    for (int mi = 0; mi < 4; mi++)
      af[mi] = *(const bf16x8*)&As[(wm * 64 + mi * 16 + r16) * 32 + quad * 8];
#pragma unroll
    for (int ni = 0; ni < 4; ni++)
      bfv[ni] = *(const bf16x8*)&Bs[(wn * 64 + ni * 16 + r16) * 32 + quad * 8];
#pragma unroll
    for (int mi = 0; mi < 4; mi++)
#pragma unroll
      for (int ni = 0; ni < 4; ni++)
        acc[mi][ni] = __builtin_amdgcn_mfma_f32_16x16x32_bf16(af[mi], bfv[ni],
                                                              acc[mi][ni], 0, 0, 0);
    __syncthreads();
  }

  // C/D layout: col = lane&15, row = quad*4 + reg  (m89/m91-verified)
  if constexpr (EPI == 0) {
    // Phase 1: tsum[r][c] = T_go[go[r]][c] + T_to[to[r]][c] + bias[c], coalesced.
    float* tsum = (float*)smem;                 // [128][132], pad -> 2-way banks
#pragma unroll
    for (int i = 0; i < 16; i++) {
      int c = i * 256 + tid;                    // 4096 f32x4 chunks
      int r = c >> 5, ch = c & 31;
      long grow = rowbase + r;
      const float* tg = Ttab + (long)go_off[grow] * 1024 + colbase;
      const float* tt = Ttab + 361L * 1024 + (long)to_off[grow] * 1024 + colbase;
      f32x4 a = *(const f32x4*)(tg + ch * 4);
      f32x4 b = *(const f32x4*)(tt + ch * 4);
      f32x4 d = *(const f32x4*)(bias + colbase + ch * 4);
      f32x4 s = a + b + d;
      *(f32x4*)&tsum[r * 132 + ch * 4] = s;
    }
    __syncthreads();
    // Phase 2: v = acc + tsum, relu, bf16 — hold packed in regs (tsum aliased by Cs).
    unsigned int hreg[4][4][2];
#pragma unroll
    for (int mi = 0; mi < 4; mi++) {
#pragma unroll
      for (int reg = 0; reg < 4; reg++) {
        int rloc = wm * 64 + mi * 16 + quad * 4 + reg;
        unsigned int p0 = 0, p1 = 0;
#pragma unroll
        for (int ni = 0; ni < 4; ni++) {
          int cloc = wn * 64 + ni * 16 + r16;
          float v = acc[mi][ni][reg] + tsum[rloc * 132 + cloc];
          unsigned int us = f2bf(fmaxf(v, 0.f));
          if (ni == 0) p0 = us;
          else if (ni == 1) p0 |= us << 16;
          else if (ni == 2) p1 = us;
          else p1 |= us << 16;
        }
        hreg[mi][reg][0] = p0;
        hreg[mi][reg][1] = p1;
      }
    }
    __syncthreads();
    // Phase 3: restage bf16 tile (stride 136) then 16B-coalesced global stores.
    unsigned short* Cs = (unsigned short*)smem;  // [128][136]
#pragma unroll
    for (int mi = 0; mi < 4; mi++) {
#pragma unroll
      for (int reg = 0; reg < 4; reg++) {
        int rloc = wm * 64 + mi * 16 + quad * 4 + reg;
#pragma unroll
        for (int ni = 0; ni < 4; ni++) {
          int cloc = wn * 64 + ni * 16 + r16;
          Cs[rloc * 136 + cloc] =
              (unsigned short)(hreg[mi][reg][ni >> 1] >> ((ni & 1) * 16));
        }
      }
    }
    __syncthreads();
#pragma unroll
    for (int i = 0; i < 8; i++) {
      int c = i * 256 + tid;
      int r = c >> 4;
      int cc = c & 15;
      *(i32x4*)(h1out + (rowbase + r) * 1024 + colbase + cc * 8) =
          *(const i32x4*)&Cs[r * 136 + cc * 8];
    }
  } else {
#pragma unroll
    for (int mi = 0; mi < 4; mi++) {
#pragma unroll
      for (int reg = 0; reg < 4; reg++) {
        long row = rowbase + wm * 64 + mi * 16 + quad * 4 + reg;
        float part = 0.f;
#pragma unroll
        for (int ni = 0; ni < 4; ni++) {
          int col = colbase + wn * 64 + ni * 16 + r16;
          float v = fmaxf(acc[mi][ni][reg] + bias[col], 0.f);
          part += v * w3[col];
        }
        part += __shfl_xor(part, 1, 16);
        part += __shfl_xor(part, 2, 16);
        part += __shfl_xor(part, 4, 16);
        part += __shfl_xor(part, 8, 16);
        if (r16 == 0) atomicAdd(&scores[row], part);
      }
    }
  }
}

// ---------------------------------------------------------------- launch

extern "C" void kernel_launch(void* const* d_in, const int* in_sizes, int n_in,
                              void* d_out, int out_size, void* d_ws, size_t ws_size,
                              hipStream_t stream) {
  const float* pfm  = (const float*)d_in[0];  // (256,19,19)
  const float* cand = (const float*)d_in[1];  // (65536,64)
  const float* W1   = (const float*)d_in[2];  // (832,1024)
  const float* b1   = (const float*)d_in[3];  // (1024,)
  const float* W2   = (const float*)d_in[4];  // (1024,1024)
  const float* b2   = (const float*)d_in[5];  // (1024,)
  const float* W3   = (const float*)d_in[6];  // (1024,1)
  const float* b3   = (const float*)d_in[7];  // (1,)
  float* scores = (float*)d_out;              // (65536,)

  char* ws = (char*)d_ws;
  float*          gp      = (float*)(ws + 0);          //   1 KB
  float*          b1p     = (float*)(ws + 1024);       //   4 KB
  float*          Ttab    = (float*)(ws + 8192);       // 2*361*1024*4 = 2.83 MB
  int*            go_off  = (int*)(ws + 2965504);      // 256 KB
  int*            to_off  = (int*)(ws + 3227648);      // 256 KB
  unsigned short* cand_bf = (unsigned short*)(ws + 3489792);   // 8 MB
  unsigned short* w1cT    = (unsigned short*)(ws + 11878400);  // 128 KB
  unsigned short* w2T     = (unsigned short*)(ws + 12009472);  // 2 MB
  unsigned short* h1      = (unsigned short*)(ws + 14106624);  // 128 MB
  // total ws need: 148,324,352 bytes
  if (ws_size < 148324352) return;  // loud correctness failure instead of corruption

  misc_kernel<<<17156, 256, 0, stream>>>(cand, cand_bf, go_off, to_off, scores, b3,
                                         b1, b1p, W1, w1cT);
  pool_kernel<<<256, 64, 0, stream>>>(pfm, gp);
  b1p_kernel<<<128, 256, 0, stream>>>(W1, gp, b1p);
  ttab_kernel<<<368, 256, 0, stream>>>(pfm, W1, Ttab);
  w2t_kernel<<<256, 256, 0, stream>>>(W2, w2T);

  // h1 = relu(cand@W1c + T_go[g] + T_to[t] + b1')   M=65536,K=64
  gemm_bt<0><<<4096, 256, 0, stream>>>(cand_bf, w1cT, 64, h1, Ttab, go_off, to_off,
                                       b1p, nullptr, nullptr);
  // scores += relu(h1@W2 + b2) @ w3                 M=65536,K=1024
  gemm_bt<1><<<4096, 256, 0, stream>>>(h1, w2T, 1024, nullptr, nullptr, nullptr,
                                       nullptr, b2, W3, scores);
}

// Round 4
// 286.942 us; speedup vs baseline: 1.1583x; 1.1583x over previous
//
#include <hip/hip_runtime.h>

// CandidateScorer on MI355X (gfx950).
//
// Math (exact rewrite of the reference):
//   gp-part of combined is candidate-independent      -> folded into bias b1'
//   go/to gathers take only 361 distinct values each  -> precomputed tables
//   h1[n,j] = relu(T_go[go[n],j] + T_to[to[n],j] + (cand @ W1c)[n,j] + b1'[j])
//   scores  = relu(h1 @ W2 + b2) @ W3 + b3   (GEMM3 fused into GEMM2 epilogue)
//
// R1: XCD-aware swizzle (GEMM2 FETCH 529->93 MB), LDS-staged h1 stores.
// R2: tail kernels rework (neutral -> tail is not the small preps).
// R3: GEMM2 BK=64 + XOR-swizzled LDS (halve barrier count; swizzle keeps
//     b128 frag reads bank-balanced without padding, since global_load_lds
//     forbids padded LDS rows). GEMM1: bf16 in-place tsum (LDS 67.6->34.8 KB,
//     2->4 blocks/CU), cand f32->bf16 folded into A-staging.

using bf16x8 = __attribute__((ext_vector_type(8))) __bf16;
using f32x4  = __attribute__((ext_vector_type(4))) float;
using i32x4  = __attribute__((ext_vector_type(4))) int;

__device__ __forceinline__ unsigned short f2bf(float f) {
  unsigned int u = __float_as_uint(f);
  u += 0x7fffu + ((u >> 16) & 1u);          // round-to-nearest-even
  return (unsigned short)(u >> 16);
}
__device__ __forceinline__ float bf2f(unsigned short s) {
  return __uint_as_float(((unsigned int)s) << 16);
}

// Async global->LDS, 16B per lane. LDS dest is wave-uniform base + lane*16.
__device__ __forceinline__ void async_copy16(const void* g, void* l) {
  __builtin_amdgcn_global_load_lds(
      (__attribute__((address_space(1))) void*)(unsigned long long)g,
      (__attribute__((address_space(3))) void*)(unsigned int)(unsigned long long)l,
      16, 0, 0);
}

// ---------------------------------------------------------------- prep kernels

// gp[c] = mean over 19x19 of pfm[c]. one wave per channel.
__global__ void pool_kernel(const float* __restrict__ pfm, float* __restrict__ gp) {
  int c = blockIdx.x;
  int lane = threadIdx.x;
  float s = 0.f;
  for (int i = lane; i < 361; i += 64) s += pfm[c * 361 + i];
#pragma unroll
  for (int off = 32; off > 0; off >>= 1) s += __shfl_down(s, off, 64);
  if (lane == 0) gp[c] = s * (1.0f / 361.0f);
}

// b1p[j] += sum over 8 channels of gp[c] * W1[512+c][j]  (b1p pre-init to b1)
__global__ void b1p_kernel(const float* __restrict__ W1, const float* __restrict__ gp,
                           float* __restrict__ b1p) {
  int bx = blockIdx.x;
  int j = (bx & 3) * 256 + threadIdx.x;
  int c0 = (bx >> 2) * 8;
  float acc = 0.f;
#pragma unroll
  for (int i = 0; i < 8; i++)
    acc += gp[c0 + i] * W1[(size_t)(512 + c0 + i) * 1024 + j];
  atomicAdd(&b1p[j], acc);
}

// T[s][pos][j] = sum_c pfm[c][pos] * W1[s*256+c][j]; 8 positions per block.
__global__ void ttab_kernel(const float* __restrict__ pfm, const float* __restrict__ W1,
                            float* __restrict__ T) {
  int bx = blockIdx.x;              // 2 * 46 * 4 = 368 blocks
  int s = bx / 184;
  int rem = bx % 184;
  int p8 = rem >> 2;
  int jc = rem & 3;
  int t = threadIdx.x;
  int j = jc * 256 + t;
  __shared__ float pf[8][256];
#pragma unroll
  for (int i = 0; i < 8; i++) {
    int p = p8 * 8 + i;
    pf[i][t] = (p < 361) ? pfm[t * 361 + p] : 0.f;   // t = channel
  }
  __syncthreads();
  float acc[8] = {0.f, 0.f, 0.f, 0.f, 0.f, 0.f, 0.f, 0.f};
  for (int c = 0; c < 256; c++) {
    float w = W1[(size_t)(s * 256 + c) * 1024 + j];
#pragma unroll
    for (int i = 0; i < 8; i++) acc[i] += pf[i][c] * w;
  }
#pragma unroll
  for (int i = 0; i < 8; i++) {
    int p = p8 * 8 + i;
    if (p < 361) T[((size_t)s * 361 + p) * 1024 + j] = acc[i];
  }
}

// Fused small jobs, partitioned by block range:
//   [0,256)    go/to decode
//   [256,512)  scores = b3
//   [512,516)  b1p = b1          (atomic target init; runs before b1p_kernel)
//   [516,772)  w1cT[n][k] = bf16(W1[768+k][n])
__global__ void misc_kernel(const float* __restrict__ cand,
                            int* __restrict__ go_off, int* __restrict__ to_off,
                            float* __restrict__ scores, const float* __restrict__ b3,
                            const float* __restrict__ b1, float* __restrict__ b1p,
                            const float* __restrict__ W1, unsigned short* __restrict__ w1cT) {
  int bx = blockIdx.x, t = threadIdx.x;
  if (bx < 256) {
    int n = bx * 256 + t;
    const float* cf = cand + (size_t)n * 64;
    int gr = min(max((int)(cf[5] * 18.0f), 0), 18);
    int gc = min(max((int)(cf[6] * 18.0f), 0), 18);
    int tr = min(max((int)(cf[7] * 18.0f), 0), 18);
    int tc = min(max((int)(cf[8] * 18.0f), 0), 18);
    go_off[n] = gr * 19 + gc;
    to_off[n] = tr * 19 + tc;
  } else if (bx < 512) {
    scores[(bx - 256) * 256 + t] = b3[0];
  } else if (bx < 516) {
    int j = (bx - 512) * 256 + t;
    b1p[j] = b1[j];
  } else {
    int o = (bx - 516) * 256 + t;  // < 65536
    int n = o >> 6, k = o & 63;
    w1cT[o] = f2bf(W1[(size_t)(768 + k) * 1024 + n]);
  }
}

// w2T[n][k] = bf16(W2[k][n]) via 64x64 LDS tiles — coalesced on both sides.
__global__ void w2t_kernel(const float* __restrict__ W2, unsigned short* __restrict__ w2T) {
  __shared__ float Ts[64][65];
  int bx = blockIdx.x;              // 256 tiles (16 x 16)
  int kt = bx >> 4, nt = bx & 15;
  int tid = threadIdx.x;
#pragma unroll
  for (int i = 0; i < 4; i++) {
    int c = i * 256 + tid;          // 1024 f32x4 chunks
    int r = c >> 4, ch = c & 15;
    f32x4 v = *(const f32x4*)&W2[(size_t)(kt * 64 + r) * 1024 + nt * 64 + ch * 4];
    Ts[r][ch * 4 + 0] = v[0]; Ts[r][ch * 4 + 1] = v[1];
    Ts[r][ch * 4 + 2] = v[2]; Ts[r][ch * 4 + 3] = v[3];
  }
  __syncthreads();
#pragma unroll
  for (int i = 0; i < 2; i++) {
    int c = i * 256 + tid;          // 512 out-chunks of 8 bf16
    int n = c >> 3, ch = c & 7;
    unsigned short pack[8];
#pragma unroll
    for (int j = 0; j < 8; j++) pack[j] = f2bf(Ts[ch * 8 + j][n]);
    *(i32x4*)&w2T[(size_t)(nt * 64 + n) * 1024 + kt * 64 + ch * 8] = *(i32x4*)pack;
  }
}

// ---------------------------------------------------------------- GEMM1 (fused)

// h1(65536 x 1024) = relu(cand(f32,65536x64) @ W1c^T-prepped + T_go + T_to + b1p)
// 128x128 tile, K=64 (single staged step). A staged via f32 load + convert +
// ds_write (folds the cand->bf16 conversion); B via async_copy16.
// LDS layout XOR-swizzled: chunk (row, s) holds logical kchunk s^(row&7).
__launch_bounds__(256, 2)
__global__ void gemm1_kernel(const float* __restrict__ cand,
                             const unsigned short* __restrict__ w1cT,
                             unsigned short* __restrict__ h1out,
                             const float* __restrict__ Ttab,
                             const int* __restrict__ go_off,
                             const int* __restrict__ to_off,
                             const float* __restrict__ bias) {
  __shared__ __align__(16) char smem[34816];           // max(32K stage, 34K Cs)
  unsigned short* As = (unsigned short*)smem;          // [128][64] 16KB
  unsigned short* Bs = (unsigned short*)(smem + 16384);// [128][64] 16KB
  unsigned short* Cs = (unsigned short*)smem;          // [128][136] bf16 (aliased)

  const int tid  = threadIdx.x;
  const int lane = tid & 63;
  const int wave = tid >> 6;
  const int wm   = wave & 1;
  const int wn   = wave >> 1;
  const int quad = lane >> 4;
  const int r16  = lane & 15;

  const int bx    = blockIdx.x;
  const int xcd   = bx & 7;
  const int seq   = bx >> 3;
  const int ntile = seq & 7;
  const int mtile = ((seq >> 3) << 3) | xcd;
  const long rowbase = (long)mtile * 128;
  const int  colbase = ntile * 128;

  // ---- stage A: load f32, convert, ds_write (4 chunks of 16B per thread)
#pragma unroll
  for (int i = 0; i < 4; i++) {
    int c = i * 256 + tid;                 // physical chunk
    int row = c >> 3, s = c & 7;
    int kc = s ^ (row & 7);                // logical k-chunk
    const float* src = cand + (rowbase + row) * 64 + kc * 8;
    f32x4 v0 = *(const f32x4*)src;
    f32x4 v1 = *(const f32x4*)(src + 4);
    unsigned int p[4];
    p[0] = f2bf(v0[0]) | ((unsigned int)f2bf(v0[1]) << 16);
    p[1] = f2bf(v0[2]) | ((unsigned int)f2bf(v0[3]) << 16);
    p[2] = f2bf(v1[0]) | ((unsigned int)f2bf(v1[1]) << 16);
    p[3] = f2bf(v1[2]) | ((unsigned int)f2bf(v1[3]) << 16);
    *(i32x4*)&As[c * 8] = *(i32x4*)p;
  }
  // ---- stage B: async copy w1cT tile (4 chunks per thread)
#pragma unroll
  for (int i = 0; i < 4; i++) {
    int c = i * 256 + tid;
    int row = c >> 3, s = c & 7;
    int kc = s ^ (row & 7);
    async_copy16(w1cT + (colbase + row) * 64 + kc * 8, &Bs[c * 8]);
  }
  __syncthreads();

  const f32x4 zero4 = {0.f, 0.f, 0.f, 0.f};
  f32x4 acc[4][4];
#pragma unroll
  for (int i = 0; i < 4; i++)
#pragma unroll
    for (int j = 0; j < 4; j++) acc[i][j] = zero4;

#pragma unroll
  for (int ks = 0; ks < 2; ks++) {
    bf16x8 af[4], bfv[4];
#pragma unroll
    for (int mi = 0; mi < 4; mi++) {
      int r = wm * 64 + mi * 16 + r16;
      int phys = (ks * 4 + quad) ^ (r16 & 7);
      af[mi] = *(const bf16x8*)&As[r * 64 + phys * 8];
    }
#pragma unroll
    for (int ni = 0; ni < 4; ni++) {
      int r = wn * 64 + ni * 16 + r16;
      int phys = (ks * 4 + quad) ^ (r16 & 7);
      bfv[ni] = *(const bf16x8*)&Bs[r * 64 + phys * 8];
    }
#pragma unroll
    for (int mi = 0; mi < 4; mi++)
#pragma unroll
      for (int ni = 0; ni < 4; ni++)
        acc[mi][ni] = __builtin_amdgcn_mfma_f32_16x16x32_bf16(af[mi], bfv[ni],
                                                              acc[mi][ni], 0, 0, 0);
  }
  __syncthreads();   // staging LDS dead; Cs takes over

  // Phase 1: Cs[r][c] = bf16(T_go[go[r]][c] + T_to[to[r]][c] + bias[c]), coalesced.
#pragma unroll
  for (int i = 0; i < 16; i++) {
    int c = i * 256 + tid;                    // 4096 f32x4-quads
    int r = c >> 5, ch = c & 31;
    long grow = rowbase + r;
    const float* tg = Ttab + (long)go_off[grow] * 1024 + colbase;
    const float* tt = Ttab + 361L * 1024 + (long)to_off[grow] * 1024 + colbase;
    f32x4 a = *(const f32x4*)(tg + ch * 4);
    f32x4 b = *(const f32x4*)(tt + ch * 4);
    f32x4 d = *(const f32x4*)(bias + colbase + ch * 4);
    f32x4 s = a + b + d;
    unsigned int p0 = f2bf(s[0]) | ((unsigned int)f2bf(s[1]) << 16);
    unsigned int p1 = f2bf(s[2]) | ((unsigned int)f2bf(s[3]) << 16);
    *(unsigned long long*)&Cs[r * 136 + ch * 4] =
        (unsigned long long)p0 | ((unsigned long long)p1 << 32);
  }
  __syncthreads();
  // Phase 2: in-place RMW — each (rloc,cloc) touched by exactly one thread.
  // C/D layout: col = lane&15, row = quad*4 + reg  (m89/m91-verified)
#pragma unroll
  for (int mi = 0; mi < 4; mi++) {
#pragma unroll
    for (int reg = 0; reg < 4; reg++) {
      int rloc = wm * 64 + mi * 16 + quad * 4 + reg;
#pragma unroll
      for (int ni = 0; ni < 4; ni++) {
        int cloc = wn * 64 + ni * 16 + r16;
        float v = acc[mi][ni][reg] + bf2f(Cs[rloc * 136 + cloc]);
        Cs[rloc * 136 + cloc] = f2bf(fmaxf(v, 0.f));
      }
    }
  }
  __syncthreads();
  // Phase 3: 16B-coalesced global stores.
#pragma unroll
  for (int i = 0; i < 8; i++) {
    int c = i * 256 + tid;
    int r = c >> 4, cc = c & 15;
    *(i32x4*)(h1out + (rowbase + r) * 1024 + colbase + cc * 8) =
        *(const i32x4*)&Cs[r * 136 + cc * 8];
  }
}

// ---------------------------------------------------------------- GEMM2 (fused)

// scores += relu(h1(65536x1024,bf16) @ W2 + b2) @ W3.  BK=64, XOR-swizzled LDS,
// 16 K-iterations (halved barrier count vs BK=32).
__launch_bounds__(256, 2)
__global__ void gemm2_kernel(const unsigned short* __restrict__ A,
                             const unsigned short* __restrict__ BT,
                             const float* __restrict__ bias,
                             const float* __restrict__ w3,
                             float* __restrict__ scores) {
  __shared__ unsigned short As[128 * 64];  // [row][k] 16KB
  __shared__ unsigned short Bs[128 * 64];  // [n][k]   16KB

  const int tid  = threadIdx.x;
  const int lane = tid & 63;
  const int wave = tid >> 6;
  const int wm   = wave & 1;
  const int wn   = wave >> 1;
  const int quad = lane >> 4;
  const int r16  = lane & 15;

  const int bx    = blockIdx.x;
  const int xcd   = bx & 7;
  const int seq   = bx >> 3;
  const int ntile = seq & 7;
  const int mtile = ((seq >> 3) << 3) | xcd;
  const long rowbase = (long)mtile * 128;
  const int  colbase = ntile * 128;

  const f32x4 zero4 = {0.f, 0.f, 0.f, 0.f};
  f32x4 acc[4][4];
#pragma unroll
  for (int i = 0; i < 4; i++)
#pragma unroll
    for (int j = 0; j < 4; j++) acc[i][j] = zero4;

  // epilogue constants hoisted (8 scalar loads, L2-resident)
  float bias_r[4], w3_r[4];
#pragma unroll
  for (int ni = 0; ni < 4; ni++) {
    int col = colbase + wn * 64 + ni * 16 + r16;
    bias_r[ni] = bias[col];
    w3_r[ni]   = w3[col];
  }

  // staging: 1024 chunks/matrix; thread owns 4 A-chunks + 4 B-chunks per iter.
  int srow[4], skc[4];
#pragma unroll
  for (int i = 0; i < 4; i++) {
    int c = i * 256 + tid;
    srow[i] = c >> 3;
    skc[i]  = (c & 7) ^ (srow[i] & 7);
  }

  for (int k0 = 0; k0 < 1024; k0 += 64) {
#pragma unroll
    for (int i = 0; i < 4; i++) {
      int c = i * 256 + tid;
      async_copy16(A + (rowbase + srow[i]) * 1024 + k0 + skc[i] * 8, &As[c * 8]);
    }
#pragma unroll
    for (int i = 0; i < 4; i++) {
      int c = i * 256 + tid;
      async_copy16(BT + (long)(colbase + srow[i]) * 1024 + k0 + skc[i] * 8, &Bs[c * 8]);
    }
    __syncthreads();

#pragma unroll
    for (int ks = 0; ks < 2; ks++) {
      bf16x8 af[4], bfv[4];
#pragma unroll
      for (int mi = 0; mi < 4; mi++) {
        int r = wm * 64 + mi * 16 + r16;
        int phys = (ks * 4 + quad) ^ (r16 & 7);
        af[mi] = *(const bf16x8*)&As[r * 64 + phys * 8];
      }
#pragma unroll
      for (int ni = 0; ni < 4; ni++) {
        int r = wn * 64 + ni * 16 + r16;
        int phys = (ks * 4 + quad) ^ (r16 & 7);
        bfv[ni] = *(const bf16x8*)&Bs[r * 64 + phys * 8];
      }
#pragma unroll
      for (int mi = 0; mi < 4; mi++)
#pragma unroll
        for (int ni = 0; ni < 4; ni++)
          acc[mi][ni] = __builtin_amdgcn_mfma_f32_16x16x32_bf16(af[mi], bfv[ni],
                                                                acc[mi][ni], 0, 0, 0);
    }
    __syncthreads();
  }

  // epilogue: relu(x + b2) dot w3, shfl-reduce over 16 cols, one atomic per row.
#pragma unroll
  for (int mi = 0; mi < 4; mi++) {
#pragma unroll
    for (int reg = 0; reg < 4; reg++) {
      long row = rowbase + wm * 64 + mi * 16 + quad * 4 + reg;
      float part = 0.f;
#pragma unroll
      for (int ni = 0; ni < 4; ni++) {
        float v = fmaxf(acc[mi][ni][reg] + bias_r[ni], 0.f);
        part += v * w3_r[ni];
      }
      part += __shfl_xor(part, 1, 16);
      part += __shfl_xor(part, 2, 16);
      part += __shfl_xor(part, 4, 16);
      part += __shfl_xor(part, 8, 16);
      if (r16 == 0) atomicAdd(&scores[row], part);
    }
  }
}

// ---------------------------------------------------------------- launch

extern "C" void kernel_launch(void* const* d_in, const int* in_sizes, int n_in,
                              void* d_out, int out_size, void* d_ws, size_t ws_size,
                              hipStream_t stream) {
  const float* pfm  = (const float*)d_in[0];  // (256,19,19)
  const float* cand = (const float*)d_in[1];  // (65536,64)
  const float* W1   = (const float*)d_in[2];  // (832,1024)
  const float* b1   = (const float*)d_in[3];  // (1024,)
  const float* W2   = (const float*)d_in[4];  // (1024,1024)
  const float* b2   = (const float*)d_in[5];  // (1024,)
  const float* W3   = (const float*)d_in[6];  // (1024,1)
  const float* b3   = (const float*)d_in[7];  // (1,)
  float* scores = (float*)d_out;              // (65536,)

  char* ws = (char*)d_ws;
  float*          gp      = (float*)(ws + 0);          //   1 KB
  float*          b1p     = (float*)(ws + 1024);       //   4 KB
  float*          Ttab    = (float*)(ws + 8192);       // 2*361*1024*4 = 2.83 MB
  int*            go_off  = (int*)(ws + 2965504);      // 256 KB
  int*            to_off  = (int*)(ws + 3227648);      // 256 KB
  unsigned short* w1cT    = (unsigned short*)(ws + 3489792);   // 128 KB
  unsigned short* w2T     = (unsigned short*)(ws + 3620864);   // 2 MB
  unsigned short* h1      = (unsigned short*)(ws + 5718016);   // 128 MB
  // total ws need: 139,935,744 bytes
  if (ws_size < 139935744) return;  // loud correctness failure instead of corruption

  misc_kernel<<<772, 256, 0, stream>>>(cand, go_off, to_off, scores, b3,
                                       b1, b1p, W1, w1cT);
  pool_kernel<<<256, 64, 0, stream>>>(pfm, gp);
  b1p_kernel<<<128, 256, 0, stream>>>(W1, gp, b1p);
  ttab_kernel<<<368, 256, 0, stream>>>(pfm, W1, Ttab);
  w2t_kernel<<<256, 256, 0, stream>>>(W2, w2T);

  // h1 = relu(cand@W1c + T_go[g] + T_to[t] + b1')   M=65536,K=64
  gemm1_kernel<<<4096, 256, 0, stream>>>(cand, w1cT, h1, Ttab, go_off, to_off, b1p);
  // scores += relu(h1@W2 + b2) @ w3                 M=65536,K=1024
  gemm2_kernel<<<4096, 256, 0, stream>>>(h1, w2T, b2, W3, scores);
}